// Round 8
// baseline (169.506 us; speedup 1.0000x reference)
//
#include <hip/hip_runtime.h>
#include <math.h>

#define TOKENS 16384
#define HIDDEN 2048
#define NEXP   64
#define MBLK   32                 // tokens per block
#define NCHUNK 4                  // K chunks — wave=chunk; bit-exact vs R1/R5/R6
#define KCH    512                // k per chunk
#define KBLK   16                 // k per staged round
#define NTILE  (KCH / KBLK)       // 32 rounds
#define XPAD   16                 // row stride (floats); reads/writes at bank floor
#define RPAD   68
#define TOPK   6
#define NGROUP 8
#define TOPKG  3

__global__ __launch_bounds__(256, 2)
void moe_gate_kernel(const float* __restrict__ X, const float* __restrict__ W,
                     float* __restrict__ out, int half_out)
{
    // double-buffered wave-private tiles
    __shared__ float xs[NCHUNK][2][MBLK][XPAD];  // 4*2*32*16*4 = 16384 B
    __shared__ float ws[NCHUNK][2][NEXP][XPAD];  // 4*2*64*16*4 = 32768 B
    __shared__ float red[MBLK][RPAD];            // 32*68*4    =  8704 B (57856)

    const int tid  = threadIdx.x;
    const int wv   = __builtin_amdgcn_readfirstlane(tid >> 6); // wave = K chunk
    const int lane = tid & 63;
    const int lr   = lane >> 3;       // 0..7 token-row group
    const int lc   = lane & 7;        // 0..7 expert-col group
    const int row0 = blockIdx.x * MBLK;
    const int kb0  = wv * KCH;

    // staging maps: W: 4 lanes/row (float4), 4 row-groups of 16; X: 2 lanes/row
    const int sr = lane >> 2, sc = lane & 3;   // W
    const int xr = lane >> 1, xc = lane & 1;   // X

    float acc[4][8];
#pragma unroll
    for (int i = 0; i < 4; ++i)
#pragma unroll
        for (int j = 0; j < 8; ++j) acc[i][j] = 0.f;

    const float* xb = X + (size_t)row0 * HIDDEN + kb0;
    const float* wb = W + kb0;

#define LOADX(dst, rr)  { const float* p_ = xb + (size_t)(rr) * KBLK;               \
        dst[0] = *(const float4*)(p_ + (size_t)xr * HIDDEN + xc * 8);               \
        dst[1] = *(const float4*)(p_ + (size_t)xr * HIDDEN + xc * 8 + 4); }
#define LOADW(dst, rr)  { const float* p_ = wb + (size_t)(rr) * KBLK;               \
        dst[0] = *(const float4*)(p_ + (size_t)(sr) * HIDDEN + sc * 4);             \
        dst[1] = *(const float4*)(p_ + (size_t)(16 + sr) * HIDDEN + sc * 4);        \
        dst[2] = *(const float4*)(p_ + (size_t)(32 + sr) * HIDDEN + sc * 4);        \
        dst[3] = *(const float4*)(p_ + (size_t)(48 + sr) * HIDDEN + sc * 4); }
#define STORE(xsrc, wsrc, bf) {                                                     \
        *(float4*)&xs[wv][bf][xr][xc * 8] = xsrc[0];                                \
        *(float4*)&xs[wv][bf][xr][xc * 8 + 4] = xsrc[1];                            \
        *(float4*)&ws[wv][bf][sr][sc * 4] = wsrc[0];                                \
        *(float4*)&ws[wv][bf][16 + sr][sc * 4] = wsrc[1];                           \
        *(float4*)&ws[wv][bf][32 + sr][sc * 4] = wsrc[2];                           \
        *(float4*)&ws[wv][bf][48 + sr][sc * 4] = wsrc[3]; }
#define COMPUTE(bf) {                                                               \
        _Pragma("unroll")                                                           \
        for (int k4 = 0; k4 < 4; ++k4) {                                            \
            float4 a[4], b[8];                                                      \
            _Pragma("unroll")                                                       \
            for (int i = 0; i < 4; ++i)                                             \
                a[i] = *(const float4*)&xs[wv][bf][i * 8 + lr][k4 * 4];             \
            _Pragma("unroll")                                                       \
            for (int j = 0; j < 8; ++j)                                             \
                b[j] = *(const float4*)&ws[wv][bf][j * 8 + lc][k4 * 4];             \
            _Pragma("unroll")                                                       \
            for (int i = 0; i < 4; ++i)                                             \
                _Pragma("unroll")                                                   \
                for (int j = 0; j < 8; ++j) {                                       \
                    float v = acc[i][j];                                            \
                    v = fmaf(a[i].x, b[j].x, v);                                    \
                    v = fmaf(a[i].y, b[j].y, v);                                    \
                    v = fmaf(a[i].z, b[j].z, v);                                    \
                    v = fmaf(a[i].w, b[j].w, v);                                    \
                    acc[i][j] = v;                                                  \
                }                                                                   \
        } }

    float4 pxA[2], pwA[4], pxB[2], pwB[4];

    // prologue: A=r0, B=r1; stage r0 into buf0
    LOADX(pxA, 0); LOADW(pwA, 0);
    LOADX(pxB, 1); LOADW(pwB, 1);
    STORE(pxA, pwA, 0);

    // steady state, unrolled x2 (named reg sets; invariant at top of even body:
    // buf[t&1] holds round t, B holds round t+1, A free)
#pragma unroll 1
    for (int t = 0; t < NTILE; t += 2) {
        // ---- round t (buf0-phase)
        if (t + 2 < NTILE) { LOADX(pxA, t + 2); LOADW(pwA, t + 2); }
        COMPUTE(t & 1);
        STORE(pxB, pwB, (t + 1) & 1);          // round t+1 -> other buffer
        // ---- round t+1
        if (t + 3 < NTILE) { LOADX(pxB, t + 3); LOADW(pwB, t + 3); }
        COMPUTE((t + 1) & 1);
        if (t + 2 < NTILE) STORE(pxA, pwA, t & 1);   // round t+2 -> this buffer
    }

    // ---- cross-chunk reduction, order 0,1,2,3 => ((c0+c1)+c2)+c3 (bit-exact)
    __syncthreads();
    if (wv == 0) {
#pragma unroll
        for (int i = 0; i < 4; ++i)
#pragma unroll
            for (int j = 0; j < 8; ++j)
                red[i * 8 + lr][j * 8 + lc] = acc[i][j];
    }
    __syncthreads();
    for (int c = 1; c < NCHUNK; ++c) {
        if (wv == c) {
#pragma unroll
            for (int i = 0; i < 4; ++i)
#pragma unroll
                for (int j = 0; j < 8; ++j)
                    red[i * 8 + lr][j * 8 + lc] += acc[i][j];
        }
        __syncthreads();
    }

    // ---- routing: one lane per token — identical code to R1 (proven)
    if (tid < MBLK) {
        const int t = tid;
        float s[NEXP];
        float m = -INFINITY;
#pragma unroll
        for (int e = 0; e < NEXP; ++e) { s[e] = red[t][e]; m = fmaxf(m, s[e]); }
        float sum = 0.f;
#pragma unroll
        for (int e = 0; e < NEXP; ++e) { s[e] = __expf(s[e] - m); sum += s[e]; }
        float inv = 1.f / sum;
#pragma unroll
        for (int e = 0; e < NEXP; ++e) s[e] *= inv;

        float gs[NGROUP];
#pragma unroll
        for (int g = 0; g < NGROUP; ++g) {
            float gm = s[g * 8];
#pragma unroll
            for (int q = 1; q < 8; ++q) gm = fmaxf(gm, s[g * 8 + q]);
            gs[g] = gm;
        }
        unsigned gmask = 0;
        for (int r = 0; r < TOPKG; ++r) {
            int bg = 0; float bv = -INFINITY;
#pragma unroll
            for (int g = 0; g < NGROUP; ++g) {
                bool avail = !((gmask >> g) & 1);
                if (avail && gs[g] > bv) { bv = gs[g]; bg = g; }
            }
            gmask |= 1u << bg;
        }
        unsigned long long chosen = 0ull;
        const int tok = row0 + t;
        for (int k = 0; k < TOPK; ++k) {
            int be = 0; float bv = -INFINITY;
#pragma unroll
            for (int e = 0; e < NEXP; ++e) {
                float v = ((gmask >> (e >> 3)) & 1u) ? s[e] : 0.f;
                bool avail = !((chosen >> e) & 1ull);
                if (avail && v > bv) { bv = v; be = e; }
            }
            chosen |= 1ull << be;
            out[(size_t)tok * TOPK + k] = (float)be;                 // idx as f32
            out[(size_t)half_out + (size_t)tok * TOPK + k] = bv;     // weight
        }
    }
}

extern "C" void kernel_launch(void* const* d_in, const int* in_sizes, int n_in,
                              void* d_out, int out_size, void* d_ws, size_t ws_size,
                              hipStream_t stream)
{
    const float* x = (const float*)d_in[0];
    const float* w = (const float*)d_in[1];
    float* out = (float*)d_out;
    const int half_out = out_size / 2;   // 98304 = 16384*6

    dim3 grid(TOKENS / MBLK);            // 512 blocks -> 2 blocks/CU
    dim3 block(256);                     // 4 waves = 4 K chunks
    moe_gate_kernel<<<grid, block, 0, stream>>>(x, w, out, half_out);
}